// Round 11
// baseline (141.106 us; speedup 1.0000x reference)
//
#include <hip/hip_runtime.h>
#include <hip/hip_bf16.h>

typedef __attribute__((ext_vector_type(8))) __bf16 bf16x8;
typedef __attribute__((ext_vector_type(4))) float f32x4;

#define N_NODES 50000
#define N_EDGES 800000
#define N_TILES 50000            // 16-edge tiles
#define WAVES 4                  // 256-thread blocks
#define TPW 5
#define NBLOCKS 2500             // 2500 * 4 * 5 = 50000 exactly

#define XS_OFF 0LL
#define XT_OFF 3200000LL         // 50000*64
#define U_OFF  6400000LL
#define WS_ELEMS 6408192LL       // + 128*64
#define WS_BYTES (WS_ELEMS * 2)

// ---- prep: convert gather tables x_s | x_t | u to bf16 in ws (r9-verified) ----
__global__ void prep_tables(const float* __restrict__ x_s,
                            const float* __restrict__ x_t,
                            const float* __restrict__ ug,
                            __bf16* __restrict__ ws) {
    long long i = (long long)(blockIdx.x * 256 + threadIdx.x) * 8;
    if (i >= WS_ELEMS) return;
    const float* src = (i < XT_OFF) ? (x_s + i)
                     : (i < U_OFF)  ? (x_t + (i - XT_OFF))
                                    : (ug  + (i - U_OFF));
    float4 f0 = *(const float4*)src;
    float4 f1 = *(const float4*)(src + 4);
    bf16x8 o;
    o[0] = (__bf16)f0.x; o[1] = (__bf16)f0.y; o[2] = (__bf16)f0.z; o[3] = (__bf16)f0.w;
    o[4] = (__bf16)f1.x; o[5] = (__bf16)f1.y; o[6] = (__bf16)f1.z; o[7] = (__bf16)f1.w;
    *(bf16x8*)(ws + i) = o;
}

template<bool BF>
__global__ __launch_bounds__(256, 3) void edge_mlp_kernel(
    const float* __restrict__ x_s, const float* __restrict__ x_t,
    const int* __restrict__ edge_index, const float* __restrict__ edge_attr,
    const float* __restrict__ ug, const int* __restrict__ batch_e,
    const float* __restrict__ W1, const float* __restrict__ b1,
    const float* __restrict__ W2, const float* __restrict__ b2,
    const __bf16* __restrict__ tbl,
    float* __restrict__ out)
{
    // LDS: 32768 + 8192 + 9728 = 50688 B -> 3 blocks/CU (12 waves/CU)
    __shared__ __align__(16) unsigned char sW1[32768];   // [n1][k] bf16, 512B rows, XOR-swz
    __shared__ __align__(16) unsigned char sW2[8192];    // [n2][n1] bf16, 128B rows, XOR-swz
    __shared__ __align__(16) __bf16 sH1[WAVES][16][76];  // [edge][n1], pad 76

    const int t = threadIdx.x;

    for (int idx = t; idx < 256 * 64; idx += 256) {
        int k = idx >> 6, n = idx & 63;
        *(__bf16*)(sW1 + n * 512 + ((k * 2) ^ ((n & 7) << 4))) = (__bf16)W1[idx];
    }
    for (int idx = t; idx < 64 * 64; idx += 256) {
        int k = idx >> 6, n = idx & 63;
        *(__bf16*)(sW2 + n * 128 + ((k * 2) ^ ((n & 7) << 4))) = (__bf16)W2[idx];
    }
    __syncthreads();

    const int wave = t >> 6;
    const int lane = t & 63;
    const int l15  = lane & 15;
    const int lk   = lane >> 4;
    const int wxor = (l15 & 7) << 4;

    float bv1[4];
    #pragma unroll
    for (int nf = 0; nf < 4; ++nf) bv1[nf] = b1[nf * 16 + l15];
    f32x4 bias2frag[4];
    #pragma unroll
    for (int mf = 0; mf < 4; ++mf)
        #pragma unroll
        for (int r = 0; r < 4; ++r)
            bias2frag[mf][r] = b2[mf * 16 + lk * 4 + r];

    const int tile_base = (blockIdx.x * WAVES + wave) * TPW;

    int srcs[TPW], tgts[TPW], bgs[TPW];
    #pragma unroll
    for (int i = 0; i < TPW; ++i) {
        const int e = (tile_base + i) * 16 + l15;
        srcs[i] = edge_index[e];
        tgts[i] = edge_index[N_EDGES + e];
        bgs[i]  = batch_e[e];
    }

    // ---- register double-buffer of per-tile A-inputs (prefetch distance 1) ----
    bf16x8 pxs[2][2], pxt[2][2];
    f32x4  pea[2][4];

    if (BF) {
        // prologue: tile 0 -> buf 0
        const __bf16* ps = tbl + XS_OFF + (long long)srcs[0] * 64 + lk * 8;
        pxs[0][0] = *(const bf16x8*)ps;
        pxs[0][1] = *(const bf16x8*)(ps + 32);
        const __bf16* pt = tbl + XT_OFF + (long long)tgts[0] * 64 + lk * 8;
        pxt[0][0] = *(const bf16x8*)pt;
        pxt[0][1] = *(const bf16x8*)(pt + 32);
        const float* pe = edge_attr + (long long)(tile_base * 16 + l15) * 64 + lk * 8;
        pea[0][0] = *(const f32x4*)pe;
        pea[0][1] = *(const f32x4*)(pe + 4);
        pea[0][2] = *(const f32x4*)(pe + 32);
        pea[0][3] = *(const f32x4*)(pe + 36);
    }

    #pragma unroll
    for (int i = 0; i < TPW; ++i) {
        const int tile = tile_base + i;
        const int e = tile * 16 + l15;
        const int cur = i & 1;
        const int nxt = (i + 1) & 1;

        // ---- issue prefetch of tile i+1 (results live across this iteration;
        //      regalloc cannot serialize them; sched_barrier pins issue slot) ----
        if (BF && (i + 1 < TPW)) {
            const int e1 = (tile + 1) * 16 + l15;
            const __bf16* ps = tbl + XS_OFF + (long long)srcs[i + 1] * 64 + lk * 8;
            pxs[nxt][0] = *(const bf16x8*)ps;
            pxs[nxt][1] = *(const bf16x8*)(ps + 32);
            const __bf16* pt = tbl + XT_OFF + (long long)tgts[i + 1] * 64 + lk * 8;
            pxt[nxt][0] = *(const bf16x8*)pt;
            pxt[nxt][1] = *(const bf16x8*)(pt + 32);
            const float* pe = edge_attr + (long long)e1 * 64 + lk * 8;
            pea[nxt][0] = *(const f32x4*)pe;
            pea[nxt][1] = *(const f32x4*)(pe + 4);
            pea[nxt][2] = *(const f32x4*)(pe + 32);
            pea[nxt][3] = *(const f32x4*)(pe + 36);
        }
        if (BF) __builtin_amdgcn_sched_barrier(0);

        // ---- u loads: 16 KB table, L1-hot; consumed at kk6-7 ----
        bf16x8 uf0, uf1;
        if (BF) {
            const __bf16* up = tbl + U_OFF + (long long)bgs[i] * 64 + lk * 8;
            uf0 = *(const bf16x8*)(up);
            uf1 = *(const bf16x8*)(up + 32);
        } else {
            const float* up = ug + (long long)bgs[i] * 64 + lk * 8;
            float4 g0 = *(const float4*)(up),      g1 = *(const float4*)(up + 4);
            float4 g2 = *(const float4*)(up + 32), g3 = *(const float4*)(up + 36);
            #pragma unroll
            for (int r = 0; r < 4; ++r) {
                uf0[r] = (__bf16)((const float*)&g0)[r]; uf0[4+r] = (__bf16)((const float*)&g1)[r];
                uf1[r] = (__bf16)((const float*)&g2)[r]; uf1[4+r] = (__bf16)((const float*)&g3)[r];
            }
        }

        // ---- GEMM1: kk0-3 regs (xs/xt), kk4-5 regs (ea, cvt here), kk6-7 u ----
        f32x4 acc[4];
        #pragma unroll
        for (int nf = 0; nf < 4; ++nf)
            acc[nf] = (f32x4){bv1[nf], bv1[nf], bv1[nf], bv1[nf]};

        #pragma unroll
        for (int kk = 0; kk < 8; ++kk) {
            bf16x8 a;
            if (BF) {
                if      (kk == 0) a = pxs[cur][0];
                else if (kk == 1) a = pxs[cur][1];
                else if (kk == 2) a = pxt[cur][0];
                else if (kk == 3) a = pxt[cur][1];
                else if (kk == 4) {
                    #pragma unroll
                    for (int r = 0; r < 4; ++r) {
                        a[r]     = (__bf16)pea[cur][0][r];
                        a[4 + r] = (__bf16)pea[cur][1][r];
                    }
                } else if (kk == 5) {
                    #pragma unroll
                    for (int r = 0; r < 4; ++r) {
                        a[r]     = (__bf16)pea[cur][2][r];
                        a[4 + r] = (__bf16)pea[cur][3][r];
                    }
                } else a = (kk == 6) ? uf0 : uf1;
            } else {
                const int k0 = kk * 32 + lk * 8;
                if (kk >= 6) a = (kk == 6) ? uf0 : uf1;
                else {
                    const float* p =
                        (k0 < 64)  ? (x_s + (long long)srcs[i] * 64 + k0) :
                        (k0 < 128) ? (x_t + (long long)tgts[i] * 64 + (k0 - 64)) :
                                     (edge_attr + (long long)e * 64 + (k0 - 128));
                    float4 f0 = *(const float4*)p;
                    float4 f1 = *(const float4*)(p + 4);
                    a[0]=(__bf16)f0.x; a[1]=(__bf16)f0.y; a[2]=(__bf16)f0.z; a[3]=(__bf16)f0.w;
                    a[4]=(__bf16)f1.x; a[5]=(__bf16)f1.y; a[6]=(__bf16)f1.z; a[7]=(__bf16)f1.w;
                }
            }
            #pragma unroll
            for (int nf = 0; nf < 4; ++nf) {
                bf16x8 b = *(const bf16x8*)(sW1 + (nf * 16 + l15) * 512 +
                                            ((kk * 64 + lk * 16) ^ wxor));
                acc[nf] = __builtin_amdgcn_mfma_f32_16x16x32_bf16(a, b, acc[nf], 0, 0, 0);
            }
        }

        // ---- LeakyReLU(0.1) -> bf16 -> sH1 (per-wave; no barrier needed) ----
        #pragma unroll
        for (int nf = 0; nf < 4; ++nf)
            #pragma unroll
            for (int r = 0; r < 4; ++r) {
                float v = acc[nf][r];
                v = fmaxf(v, 0.1f * v);
                sH1[wave][lk * 4 + r][nf * 16 + l15] = (__bf16)v;
            }

        // ---- GEMM2^T: O^T = W2^T x H1^T ----
        f32x4 acc2[4];
        #pragma unroll
        for (int mf = 0; mf < 4; ++mf) acc2[mf] = bias2frag[mf];
        #pragma unroll
        for (int kk2 = 0; kk2 < 2; ++kk2) {
            bf16x8 bh = *(const bf16x8*)&sH1[wave][l15][kk2 * 32 + lk * 8];
            #pragma unroll
            for (int mf = 0; mf < 4; ++mf) {
                bf16x8 aw = *(const bf16x8*)(sW2 + (mf * 16 + l15) * 128 +
                                             ((kk2 * 64 + lk * 16) ^ wxor));
                acc2[mf] = __builtin_amdgcn_mfma_f32_16x16x32_bf16(aw, bh, acc2[mf], 0, 0, 0);
            }
        }

        // ---- store: lane holds out[e][mf*16+lk*4 .. +3] ----
        float* orow = out + (long long)e * 64;
        #pragma unroll
        for (int mf = 0; mf < 4; ++mf)
            *(f32x4*)&orow[mf * 16 + lk * 4] = acc2[mf];
    }
}

extern "C" void kernel_launch(void* const* d_in, const int* in_sizes, int n_in,
                              void* d_out, int out_size, void* d_ws, size_t ws_size,
                              hipStream_t stream) {
    const float* x_s        = (const float*)d_in[0];
    const float* x_t        = (const float*)d_in[1];
    const int*   edge_index = (const int*)d_in[2];   // harness: integer -> int32
    const float* edge_attr  = (const float*)d_in[3];
    const float* ug         = (const float*)d_in[4];
    const int*   batch_e    = (const int*)d_in[5];
    const float* W1         = (const float*)d_in[6];
    const float* b1         = (const float*)d_in[7];
    const float* W2         = (const float*)d_in[8];
    const float* b2         = (const float*)d_in[9];
    float*       out        = (float*)d_out;

    if (ws_size >= (size_t)WS_BYTES) {
        __bf16* tbl = (__bf16*)d_ws;
        prep_tables<<<(int)((WS_ELEMS / 8 + 255) / 256), 256, 0, stream>>>(x_s, x_t, ug, tbl);
        edge_mlp_kernel<true><<<NBLOCKS, 256, 0, stream>>>(
            x_s, x_t, edge_index, edge_attr, ug, batch_e, W1, b1, W2, b2, tbl, out);
    } else {
        edge_mlp_kernel<false><<<NBLOCKS, 256, 0, stream>>>(
            x_s, x_t, edge_index, edge_attr, ug, batch_e, W1, b1, W2, b2, nullptr, out);
    }
}